// Round 3
// baseline (302.316 us; speedup 1.0000x reference)
//
#include <hip/hip_runtime.h>
#include <hip/hip_bf16.h>

// Color_Attention: transposed (channel) attention.
//   G_ic = I*C^T, G_cc = C*C^T, G_ii = I*I^T   (192x192 per batch, K=16384)
//   A_pre = Wq*G_ic^T*Wk^T ; nq = diag(Wq*G_cc*Wq^T); nk = diag(Wk*G_ii*Wk^T)
//   attn = softmax over head-diagonal 24x24 blocks of A_pre/(nq*nk)
//   P = Wo * blockdiag(attn) * Wv ; out = P @ input

typedef __attribute__((ext_vector_type(4))) float f32x4;
typedef __attribute__((ext_vector_type(8))) short short8;

#define MFMA16(a, b, c) __builtin_amdgcn_mfma_f32_16x16x32_bf16((a), (b), (c), 0, 0, 0)

__device__ __forceinline__ unsigned int pack_rne(float a, float b) {
  unsigned int ua = __float_as_uint(a), ub = __float_as_uint(b);
  ua += 0x7fffu + ((ua >> 16) & 1u);
  ub += 0x7fffu + ((ub >> 16) & 1u);
  return (ua >> 16) | (ub & 0xffff0000u);
}
__device__ __forceinline__ unsigned short bf16u_rne(float x) {
  unsigned int u = __float_as_uint(x);
  u += 0x7fffu + ((u >> 16) & 1u);
  return (unsigned short)(u >> 16);
}
union S8U { short8 s; unsigned int u[4]; };
__device__ __forceinline__ short8 load_cvt8(const float* p) {
  f32x4 x = *(const f32x4*)p;
  f32x4 y = *(const f32x4*)(p + 4);
  S8U r;
  r.u[0] = pack_rne(x[0], x[1]);
  r.u[1] = pack_rne(x[2], x[3]);
  r.u[2] = pack_rne(y[0], y[1]);
  r.u[3] = pack_rne(y[2], y[3]);
  return r.s;
}

#define HW 16384
#define CDIM 192
#define NB 8

// ---------------- Kernel 0: transpose Wv -> bf16 WvT[j][c'] ----------------
__global__ void k0_wvt(const float* __restrict__ Wv, unsigned short* __restrict__ WvT) {
  int idx = blockIdx.x * 256 + threadIdx.x;
  if (idx < CDIM * CDIM) {
    int j = idx / CDIM, cp = idx % CDIM;
    WvT[idx] = bf16u_rne(Wv[(size_t)cp * CDIM + j]);
  }
}

// ================= Gram kernels =================
// Tile: 192 rows x 32 cols bf16, 64B/row, XOR swizzle byte^=((row&3)<<4).
// KC=32 -> one K-step per chunk; LDS double buffer 2 x 12KB per tensor.

// stage: thread covers (srow=tid>>3 in 0..31, scol=(tid&7)*4), 6 rounds of 32 rows
__device__ __forceinline__ void stage_load6(const float* __restrict__ X, int col0,
                                            int tid, f32x4* v) {
  const int srow = tid >> 3, scol = (tid & 7) * 4;
  const float* p = X + (size_t)srow * HW + col0 + scol;
#pragma unroll
  for (int r = 0; r < 6; ++r) v[r] = *(const f32x4*)(p + (size_t)r * 32 * HW);
}
__device__ __forceinline__ void stage_write6(char* dst, const f32x4* v, int tid) {
  const int srow = tid >> 3, scb = (tid & 7) * 8;
  char* d = dst + srow * 64 + (scb ^ ((srow & 3) << 4));
#pragma unroll
  for (int r = 0; r < 6; ++r) {
    unsigned long long pk = (unsigned long long)pack_rne(v[r][0], v[r][1]) |
                            ((unsigned long long)pack_rne(v[r][2], v[r][3]) << 32);
    *(unsigned long long*)(d + r * 32 * 64) = pk;
  }
}
__device__ __forceinline__ short8 frag_read(const char* t, int row, int lg) {
  return *(const short8*)(t + row * 64 + ((lg * 16) ^ ((row & 3) << 4)));
}

__device__ __forceinline__ void compute_dual(const char* tX, const char* tY,
                                             f32x4 (&acc)[3][12], int l15, int lg, int wave) {
  short8 afr[3];
#pragma unroll
  for (int t = 0; t < 3; t++) afr[t] = frag_read(tX, (wave * 3 + t) * 16 + l15, lg);
#pragma unroll
  for (int tj = 0; tj < 12; tj++) {
    short8 bfr = frag_read(tY, tj * 16 + l15, lg);
#pragma unroll
    for (int t = 0; t < 3; t++) acc[t][tj] = MFMA16(afr[t], bfr, acc[t][tj]);
  }
}

template <int R0, int R1, int R2>
__device__ __forceinline__ void compute_sym(const char* tX, f32x4 (&acc)[3][12],
                                            int l15, int lg) {
  short8 afr0 = frag_read(tX, R0 * 16 + l15, lg);
  short8 afr1 = frag_read(tX, R1 * 16 + l15, lg);
  short8 afr2 = frag_read(tX, R2 * 16 + l15, lg);
#pragma unroll
  for (int tj = 0; tj < 12; tj++) {
    short8 bfr = frag_read(tX, tj * 16 + l15, lg);
    if (tj >= R0) acc[0][tj] = MFMA16(afr0, bfr, acc[0][tj]);
    if (tj >= R1) acc[1][tj] = MFMA16(afr1, bfr, acc[1][tj]);
    if (tj >= R2) acc[2][tj] = MFMA16(afr2, bfr, acc[2][tj]);
  }
}

// symmetric gram over 16 chunks (strip covers cols strip*512 .. +512)
template <int W>
__device__ __forceinline__ void sym_loop(const float* __restrict__ Xb, float* __restrict__ Gb,
                                         char* ldsA, char* ldsB, int strip, int tid, int lane) {
  const int l15 = lane & 15, lg = lane >> 4;
  constexpr int R0 = W, R1 = 11 - W, R2 = W + 4;
  f32x4 acc[3][12];
#pragma unroll
  for (int t = 0; t < 3; t++)
#pragma unroll
    for (int j = 0; j < 12; j++) acc[t][j] = (f32x4){0.f, 0.f, 0.f, 0.f};

  const int cb = strip * 16;
  {
    f32x4 v[6];
    stage_load6(Xb, cb * 32, tid, v);
    stage_write6(ldsA, v, tid);
  }
  __syncthreads();
#pragma unroll 1
  for (int c = 0; c < 16; c += 2) {
    {
      f32x4 v[6];
      stage_load6(Xb, (cb + c + 1) * 32, tid, v);
      compute_sym<R0, R1, R2>(ldsA, acc, l15, lg);
      stage_write6(ldsB, v, tid);
      __syncthreads();
    }
    {
      f32x4 v[6];
      const bool more = (c + 2 < 16);
      if (more) stage_load6(Xb, (cb + c + 2) * 32, tid, v);
      compute_sym<R0, R1, R2>(ldsB, acc, l15, lg);
      if (more) stage_write6(ldsA, v, tid);
      __syncthreads();
    }
  }
  // flush upper-triangle tiles only (tj >= row-tile)
  const int rts[3] = {R0, R1, R2};
#pragma unroll
  for (int t = 0; t < 3; t++) {
    const int m0 = rts[t] * 16 + lg * 4;
#pragma unroll
    for (int tj = 0; tj < 12; tj++) {
      if (tj < rts[t]) continue;
      const int n = tj * 16 + l15;
#pragma unroll
      for (int r = 0; r < 4; r++) atomicAdd(&Gb[(size_t)(m0 + r) * CDIM + n], acc[t][tj][r]);
    }
  }
}

// grid (64, NB, 2): z=0 -> G_ic (64 strips, 8 chunks); z=1 -> cc (strips 0-31) / ii (32-63), 16 chunks
__global__ __launch_bounds__(256, 2) void gram_k(const float* __restrict__ input,
                                                 const float* __restrict__ color,
                                                 float* __restrict__ G) {
  __shared__ __align__(16) char ldsA[24576];
  __shared__ __align__(16) char ldsB[24576];
  const int tid = threadIdx.x, wave = tid >> 6, lane = tid & 63;
  const int b = blockIdx.y;
  const size_t base = (size_t)b * CDIM * HW;

  if (blockIdx.z == 0) {
    const int strip = blockIdx.x;  // 8 chunks: cols (strip*8+c)*32
    const float* Xb = input + base;
    const float* Yb = color + base;
    float* Gb = G + (size_t)b * CDIM * CDIM;
    const int l15 = lane & 15, lg = lane >> 4;
    f32x4 acc[3][12];
#pragma unroll
    for (int t = 0; t < 3; t++)
#pragma unroll
      for (int j = 0; j < 12; j++) acc[t][j] = (f32x4){0.f, 0.f, 0.f, 0.f};
    {
      f32x4 v[12];
      stage_load6(Xb, strip * 256, tid, v);
      stage_load6(Yb, strip * 256, tid, v + 6);
      stage_write6(ldsA, v, tid);
      stage_write6(ldsA + 12288, v + 6, tid);
    }
    __syncthreads();
#pragma unroll 1
    for (int c = 0; c < 8; c += 2) {
      {
        f32x4 v[12];
        stage_load6(Xb, (strip * 8 + c + 1) * 32, tid, v);
        stage_load6(Yb, (strip * 8 + c + 1) * 32, tid, v + 6);
        compute_dual(ldsA, ldsA + 12288, acc, l15, lg, wave);
        stage_write6(ldsB, v, tid);
        stage_write6(ldsB + 12288, v + 6, tid);
        __syncthreads();
      }
      {
        f32x4 v[12];
        const bool more = (c + 2 < 8);
        if (more) {
          stage_load6(Xb, (strip * 8 + c + 2) * 32, tid, v);
          stage_load6(Yb, (strip * 8 + c + 2) * 32, tid, v + 6);
        }
        compute_dual(ldsB, ldsB + 12288, acc, l15, lg, wave);
        if (more) {
          stage_write6(ldsA, v, tid);
          stage_write6(ldsA + 12288, v + 6, tid);
        }
        __syncthreads();
      }
    }
#pragma unroll
    for (int t = 0; t < 3; t++) {
      const int m0 = wave * 48 + t * 16 + lg * 4;
#pragma unroll
      for (int tj = 0; tj < 12; tj++) {
        const int n = tj * 16 + l15;
#pragma unroll
        for (int r = 0; r < 4; r++) atomicAdd(&Gb[(size_t)(m0 + r) * CDIM + n], acc[t][tj][r]);
      }
    }
  } else {
    const int s = blockIdx.x;
    const float* Xb = (s < 32) ? (color + base) : (input + base);
    float* Gb = G + ((size_t)((s < 32) ? 1 : 2) * NB + b) * (CDIM * CDIM);
    const int strip = s & 31;  // 16 chunks: cols (strip*16+c)*32
    switch (wave) {
      case 0: sym_loop<0>(Xb, Gb, ldsA, ldsB, strip, tid, lane); break;
      case 1: sym_loop<1>(Xb, Gb, ldsA, ldsB, strip, tid, lane); break;
      case 2: sym_loop<2>(Xb, Gb, ldsA, ldsB, strip, tid, lane); break;
      default: sym_loop<3>(Xb, Gb, ldsA, ldsB, strip, tid, lane); break;
    }
  }
}

// mirror lower triangle of symmetric grams (types 1,2)
__global__ void mirror_k(float* __restrict__ G) {
  float* Gm = G + ((size_t)(1 + blockIdx.y) * NB + blockIdx.x) * (CDIM * CDIM);
  for (int i = threadIdx.x; i < CDIM * CDIM; i += 256) {
    const int m = i / CDIM, n = i - m * CDIM;
    if (m > n) Gm[i] = Gm[(size_t)n * CDIM + m];
  }
}

// ---------------- Kernel 2a: A_pre (type0), nq (type1), nk (type2) ----------
__global__ __launch_bounds__(256) void k2a(const float* __restrict__ G,
                                           const float* __restrict__ Wq,
                                           const float* __restrict__ Wk,
                                           float* __restrict__ A_pre,
                                           float* __restrict__ nqk) {
  const int b = blockIdx.x, type = blockIdx.y;
  __shared__ __align__(16) unsigned short Hs[192][200];
  const int tid = threadIdx.x, wave = tid >> 6, lane = tid & 63;
  const int l15 = lane & 15, lg = lane >> 4, row0 = wave * 48;
  const float* W1 = (type == 2) ? Wk : Wq;
  const float* Gm = G + ((size_t)type * NB + b) * (CDIM * CDIM);

  f32x4 acc[3][12];
#pragma unroll
  for (int t = 0; t < 3; t++)
#pragma unroll
    for (int j = 0; j < 12; j++) acc[t][j] = (f32x4){0.f, 0.f, 0.f, 0.f};

  for (int ks = 0; ks < 192; ks += 32) {
    short8 afr[3];
#pragma unroll
    for (int t = 0; t < 3; t++)
      afr[t] = load_cvt8(W1 + (size_t)(row0 + t * 16 + l15) * CDIM + ks + lg * 8);
#pragma unroll
    for (int tj = 0; tj < 12; tj++) {
      short8 bfr = load_cvt8(Gm + (size_t)(tj * 16 + l15) * CDIM + ks + lg * 8);
#pragma unroll
      for (int t = 0; t < 3; t++) acc[t][tj] = MFMA16(afr[t], bfr, acc[t][tj]);
    }
  }
#pragma unroll
  for (int t = 0; t < 3; t++)
#pragma unroll
    for (int tj = 0; tj < 12; tj++)
#pragma unroll
      for (int r = 0; r < 4; r++)
        Hs[row0 + t * 16 + lg * 4 + r][tj * 16 + l15] = bf16u_rne(acc[t][tj][r]);
  __syncthreads();

  if (type == 0) {
    f32x4 a2[3][12];
#pragma unroll
    for (int t = 0; t < 3; t++)
#pragma unroll
      for (int j = 0; j < 12; j++) a2[t][j] = (f32x4){0.f, 0.f, 0.f, 0.f};
    for (int ks = 0; ks < 192; ks += 32) {
      short8 afr[3];
#pragma unroll
      for (int t = 0; t < 3; t++)
        afr[t] = *(const short8*)&Hs[row0 + t * 16 + l15][ks + lg * 8];
#pragma unroll
      for (int tj = 0; tj < 12; tj++) {
        short8 bfr = load_cvt8(Wk + (size_t)(tj * 16 + l15) * CDIM + ks + lg * 8);
#pragma unroll
        for (int t = 0; t < 3; t++) a2[t][tj] = MFMA16(afr[t], bfr, a2[t][tj]);
      }
    }
    float* Ab = A_pre + (size_t)b * CDIM * CDIM;
#pragma unroll
    for (int t = 0; t < 3; t++)
#pragma unroll
      for (int tj = 0; tj < 12; tj++)
#pragma unroll
        for (int r = 0; r < 4; r++)
          Ab[(size_t)(row0 + t * 16 + lg * 4 + r) * CDIM + tj * 16 + l15] = a2[t][tj][r];
  } else {
    f32x4 a2[3];
#pragma unroll
    for (int t = 0; t < 3; t++) a2[t] = (f32x4){0.f, 0.f, 0.f, 0.f};
    for (int ks = 0; ks < 192; ks += 32) {
#pragma unroll
      for (int t = 0; t < 3; t++) {
        short8 afr = *(const short8*)&Hs[row0 + t * 16 + l15][ks + lg * 8];
        short8 bfr = load_cvt8(W1 + (size_t)(row0 + t * 16 + l15) * CDIM + ks + lg * 8);
        a2[t] = MFMA16(afr, bfr, a2[t]);
      }
    }
    float* dst = nqk + ((size_t)(type - 1) * NB + b) * CDIM;
#pragma unroll
    for (int t = 0; t < 3; t++)
#pragma unroll
      for (int r = 0; r < 4; r++)
        if (lg * 4 + r == l15) dst[row0 + t * 16 + l15] = a2[t][r];
  }
}

// ---------------- Kernel 2b: per-head softmax ----------------
__global__ void k2b(const float* __restrict__ A_pre, const float* __restrict__ nqk,
                    float* __restrict__ attnw) {
  const int b = blockIdx.x, tid = threadIdx.x;
  const int h = tid >> 5, r = tid & 31;
  if (r >= 24) return;
  const float* Ab = A_pre + (size_t)b * CDIM * CDIM;
  const float* nq = nqk + (size_t)b * CDIM;
  const float* nk = nqk + (size_t)(NB + b) * CDIM;
  const int c = h * 24 + r;
  const float qn = rsqrtf(fmaxf(nq[c], 1e-24f));
  float e[24];
  float mx = -1e30f;
#pragma unroll
  for (int d = 0; d < 24; d++) {
    float kn = rsqrtf(fmaxf(nk[h * 24 + d], 1e-24f));
    float l = Ab[(size_t)c * CDIM + h * 24 + d] * qn * kn;
    e[d] = l;
    mx = fmaxf(mx, l);
  }
  float s = 0.f;
#pragma unroll
  for (int d = 0; d < 24; d++) {
    float x = __expf(e[d] - mx);
    e[d] = x;
    s += x;
  }
  const float inv = 1.0f / s;
  float* dst = attnw + (((size_t)b * NB + h) * 24 + r) * 24;
#pragma unroll
  for (int d = 0; d < 24; d++) dst[d] = e[d] * inv;
}

// ---------------- Kernel 3: P = Wo * blockdiag(attn) * Wv  (bf16 out) -------
__global__ __launch_bounds__(256) void k3(const float* __restrict__ attnw,
                                          const float* __restrict__ Wo,
                                          const unsigned short* __restrict__ WvT,
                                          unsigned short* __restrict__ Pbf) {
  const int b = blockIdx.x;
  __shared__ __align__(16) unsigned short AT[192][200];
  __shared__ __align__(16) unsigned short Ms[192][200];
  const int tid = threadIdx.x, wave = tid >> 6, lane = tid & 63;
  const int l15 = lane & 15, lg = lane >> 4, row0 = wave * 48;

  unsigned int* ATu = (unsigned int*)&AT[0][0];
  for (int i = tid; i < 192 * 100; i += 256) ATu[i] = 0u;
  __syncthreads();
  const float* at = attnw + (size_t)b * NB * 24 * 24;
  for (int i = tid; i < 4608; i += 256) {
    int h = i / 576, rem = i % 576, c = rem / 24, d = rem % 24;
    AT[h * 24 + d][h * 24 + c] = bf16u_rne(at[(h * 24 + c) * 24 + d]);
  }
  __syncthreads();

  f32x4 acc[3][12];
#pragma unroll
  for (int t = 0; t < 3; t++)
#pragma unroll
    for (int j = 0; j < 12; j++) acc[t][j] = (f32x4){0.f, 0.f, 0.f, 0.f};
  for (int ks = 0; ks < 192; ks += 32) {
    short8 afr[3];
#pragma unroll
    for (int t = 0; t < 3; t++)
      afr[t] = load_cvt8(Wo + (size_t)(row0 + t * 16 + l15) * CDIM + ks + lg * 8);
#pragma unroll
    for (int tj = 0; tj < 12; tj++) {
      short8 bfr = *(const short8*)&AT[tj * 16 + l15][ks + lg * 8];
#pragma unroll
      for (int t = 0; t < 3; t++) acc[t][tj] = MFMA16(afr[t], bfr, acc[t][tj]);
    }
  }
#pragma unroll
  for (int t = 0; t < 3; t++)
#pragma unroll
    for (int tj = 0; tj < 12; tj++)
#pragma unroll
      for (int r = 0; r < 4; r++)
        Ms[row0 + t * 16 + lg * 4 + r][tj * 16 + l15] = bf16u_rne(acc[t][tj][r]);
  __syncthreads();

  f32x4 a2[3][12];
#pragma unroll
  for (int t = 0; t < 3; t++)
#pragma unroll
    for (int j = 0; j < 12; j++) a2[t][j] = (f32x4){0.f, 0.f, 0.f, 0.f};
  for (int ks = 0; ks < 192; ks += 32) {
    short8 afr[3];
#pragma unroll
    for (int t = 0; t < 3; t++)
      afr[t] = *(const short8*)&Ms[row0 + t * 16 + l15][ks + lg * 8];
#pragma unroll
    for (int tj = 0; tj < 12; tj++) {
      short8 bfr = *(const short8*)(WvT + (size_t)(tj * 16 + l15) * CDIM + ks + lg * 8);
#pragma unroll
      for (int t = 0; t < 3; t++) a2[t][tj] = MFMA16(afr[t], bfr, a2[t][tj]);
    }
  }
  unsigned short* Pb = Pbf + (size_t)b * CDIM * CDIM;
#pragma unroll
  for (int t = 0; t < 3; t++)
#pragma unroll
    for (int tj = 0; tj < 12; tj++)
#pragma unroll
      for (int r = 0; r < 4; r++)
        Pb[(size_t)(row0 + t * 16 + lg * 4 + r) * CDIM + tj * 16 + l15] = bf16u_rne(a2[t][tj][r]);
}

// ---------------- Kernel D: out = P @ input  ----------------
// BsT[n][k] bf16, 384B rows, XOR swizzle ((n&7)<<4): b128 fragment reads.
__global__ __launch_bounds__(256) void kD(const unsigned short* __restrict__ Pbf,
                                          const float* __restrict__ input,
                                          float* __restrict__ out) {
  const int nchunk = blockIdx.x, b = blockIdx.y;
  const int n0 = nchunk * 128;
  __shared__ __align__(16) char BsT[128 * 384];
  const int tid = threadIdx.x, wave = tid >> 6, lane = tid & 63;
  const int l15 = lane & 15, lg = lane >> 4, row0 = wave * 48;

  {
    const int n4 = (tid & 31) * 4;
    const int kb0 = (tid >> 5) * 4;
    const float* src = input + (size_t)b * CDIM * HW + n0 + n4;
#pragma unroll
    for (int rnd = 0; rnd < 6; ++rnd) {
      const int kb = kb0 + rnd * 32;
      f32x4 v0 = *(const f32x4*)(src + (size_t)(kb + 0) * HW);
      f32x4 v1 = *(const f32x4*)(src + (size_t)(kb + 1) * HW);
      f32x4 v2 = *(const f32x4*)(src + (size_t)(kb + 2) * HW);
      f32x4 v3 = *(const f32x4*)(src + (size_t)(kb + 3) * HW);
#pragma unroll
      for (int i = 0; i < 4; ++i) {
        const int n = n4 + i;
        unsigned long long pk = (unsigned long long)pack_rne(v0[i], v1[i]) |
                                ((unsigned long long)pack_rne(v2[i], v3[i]) << 32);
        *(unsigned long long*)(BsT + n * 384 + ((kb * 2) ^ ((n & 7) << 4))) = pk;
      }
    }
  }
  __syncthreads();

  f32x4 acc[3][8];
#pragma unroll
  for (int t = 0; t < 3; t++)
#pragma unroll
    for (int j = 0; j < 8; j++) acc[t][j] = (f32x4){0.f, 0.f, 0.f, 0.f};

  const unsigned short* Pb = Pbf + (size_t)b * CDIM * CDIM;
#pragma unroll 2
  for (int ks = 0; ks < 6; ks++) {
    short8 afr[3];
#pragma unroll
    for (int t = 0; t < 3; t++)
      afr[t] = *(const short8*)(Pb + (size_t)(row0 + t * 16 + l15) * CDIM + ks * 32 + lg * 8);
#pragma unroll
    for (int tn = 0; tn < 8; tn++) {
      const int n = tn * 16 + l15;
      short8 bfr = *(const short8*)(BsT + n * 384 + ((ks * 64 + lg * 16) ^ ((n & 7) << 4)));
#pragma unroll
      for (int t = 0; t < 3; t++) acc[t][tn] = MFMA16(afr[t], bfr, acc[t][tn]);
    }
  }
  float* ob = out + (size_t)b * CDIM * HW + n0;
#pragma unroll
  for (int t = 0; t < 3; t++)
#pragma unroll
    for (int tn = 0; tn < 8; tn++)
#pragma unroll
      for (int r = 0; r < 4; r++) {
        const int m = row0 + t * 16 + lg * 4 + r;
        ob[(size_t)m * HW + tn * 16 + l15] = acc[t][tn][r];
      }
}

// ---------------- launch ----------------
extern "C" void kernel_launch(void* const* d_in, const int* in_sizes, int n_in,
                              void* d_out, int out_size, void* d_ws, size_t ws_size,
                              hipStream_t stream) {
  const float* input = (const float*)d_in[0];
  const float* color = (const float*)d_in[1];
  const float* Wq = (const float*)d_in[2];
  const float* Wk = (const float*)d_in[3];
  const float* Wv = (const float*)d_in[4];
  const float* Wo = (const float*)d_in[5];
  float* out = (float*)d_out;
  char* ws = (char*)d_ws;

  const size_t OFF_G = 0;                        // 3*8*192*192*4 = 3538944
  const size_t OFF_APRE = 3538944;               // 8*192*192*4  = 1179648
  const size_t OFF_NQK = OFF_APRE + 1179648;     // 2*8*192*4    = 12288
  const size_t OFF_ATT = OFF_NQK + 12288;        // 8*8*24*24*4  = 147456
  const size_t OFF_WVT = OFF_ATT + 147456;       // 192*192*2    = 73728
  const size_t OFF_PBF = OFF_WVT + 73728;        // 8*192*192*2  = 589824

  float* G = (float*)(ws + OFF_G);
  float* A_pre = (float*)(ws + OFF_APRE);
  float* nqk = (float*)(ws + OFF_NQK);
  float* attnw = (float*)(ws + OFF_ATT);
  unsigned short* WvT = (unsigned short*)(ws + OFF_WVT);
  unsigned short* Pbf = (unsigned short*)(ws + OFF_PBF);

  hipMemsetAsync(G, 0, 3 * NB * CDIM * CDIM * sizeof(float), stream);
  k0_wvt<<<dim3(144), dim3(256), 0, stream>>>(Wv, WvT);
  gram_k<<<dim3(64, NB, 2), dim3(256), 0, stream>>>(input, color, G);
  mirror_k<<<dim3(NB, 2), dim3(256), 0, stream>>>(G);
  k2a<<<dim3(NB, 3), dim3(256), 0, stream>>>(G, Wq, Wk, A_pre, nqk);
  k2b<<<dim3(NB), dim3(256), 0, stream>>>(A_pre, nqk, attnw);
  k3<<<dim3(NB), dim3(256), 0, stream>>>(attnw, Wo, WvT, Pbf);
  kD<<<dim3(HW / 128, NB), dim3(256), 0, stream>>>(Pbf, input, out);
}